// Round 11
// baseline (302.971 us; speedup 1.0000x reference)
//
#include <hip/hip_runtime.h>

// CARAFE forward: N=8, C=128, H=64, W=64, k=5, G=1, s=2.
// out[n,c,2h+p,2w+q] = sum_{i,j} feat[n,c,h+i-2,w+j-2] * masks[n,i*5+j,2h+p,2w+q]
//
// Round 10 resubmit (round-10 bench died on GPU acquisition, never measured):
// r9 showed VGPR=68 because LDS 22016B caps 7 blocks/CU -> clang clamps the
// 8-waves/EU request to 7 -> budget 73 -> 68 -> 16-wave cap.
// Fix: drop the LDS halo (LCOLS 64) -> LDS exactly 20480B -> 8 blocks/CU
// possible -> launch_bounds(256,8) gives a real 64-VGPR budget -> 32 waves/CU.
// Edge cols handled by wrapped LDS addr ((lane+j-2)&63, hoisted per-j vaddrs)
// + cndmask-zeroing of OOB feature values (only j!=2 taps).

#define KK 5
#define PAD 2
#define CIN 128
#define HH 64
#define WW 64
#define HO 128
#define WO 128
#define NG 4                     // channel groups (= waves) per block
#define GC 4                     // channels per group, interleaved in LDS
#define CH_PER_BLOCK (NG * GC)   // 16
#define LCOLS 64                 // no halo -> 4*5*64*4*4B = 20480 B exactly

__global__ __launch_bounds__(256, 8)
void carafe_fwd(const float* __restrict__ feat,
                const float* __restrict__ masks,
                float* __restrict__ out) {
    __shared__ float lds[NG][KK][LCOLS][GC];   // 20480 B -> 8 blocks/CU

    const int tid  = threadIdx.x;
    const int lane = tid & 63;          // low-res w
    const int g    = tid >> 6;          // wave id = channel group
    // XCD swizzle: each XCD owns a contiguous h-strip of 8 (mask/halo L2 reuse).
    const int bx   = blockIdx.x;
    const int h    = ((bx & 7) << 3) | (bx >> 3);   // bijective on 0..63
    const int c0   = blockIdx.y * CH_PER_BLOCK;
    const int n    = blockIdx.z;

    // ---- stage features, 4-channel interleaved, no halo; OOB rows zeroed ----
    // 20 rowids (gg,r) x 64 cols; rowid is wave-uniform -> scalar div/mod.
    const float* fb = feat + ((size_t)n * CIN + c0) * HH * WW;
    #pragma unroll
    for (int t = 0; t < KK; ++t) {
        const int rowid = t * NG + g;   // 0..19, wave-uniform
        const int gg = rowid / KK;
        const int r  = rowid % KK;
        const int rr = h - PAD + r;
        float4 v = make_float4(0.f, 0.f, 0.f, 0.f);
        if ((unsigned)rr < (unsigned)HH) {
            const float* s = fb + ((size_t)(gg * GC) * HH + rr) * WW + lane;
            v.x = s[0 * HH * WW];
            v.y = s[1 * HH * WW];
            v.z = s[2 * HH * WW];
            v.w = s[3 * HH * WW];
        }
        *(float4*)&lds[gg][r][lane][0] = v;
    }
    __syncthreads();

    // ---- compute: per tap {1 ds_read_b128 + 2 global float2 + 16 fmac} ----
    const float* mb = masks + (size_t)n * (KK * KK) * HO * WO
                            + (size_t)(2 * h) * WO + 2 * lane;

    float2 acc[GC][2];                  // [channel][p], float2 over q
    #pragma unroll
    for (int ci = 0; ci < GC; ++ci) {
        acc[ci][0] = make_float2(0.f, 0.f);
        acc[ci][1] = make_float2(0.f, 0.f);
    }

    #pragma unroll
    for (int i = 0; i < KK; ++i) {
        #pragma unroll
        for (int j = 0; j < KK; ++j) {
            const int k   = i * KK + j;
            const int col = lane + j - PAD;           // feature column
            const bool ok = (unsigned)col < (unsigned)WW;
            // wrapped address: per-j vaddr is loop-invariant in i (hoisted);
            // i enters as the ds immediate offset (i*1024B).
            float4 f4 = *(const float4*)&lds[g][i][col & (LCOLS - 1)][0];
            const float fx = ok ? f4.x : 0.f;
            const float fy = ok ? f4.y : 0.f;
            const float fz = ok ? f4.z : 0.f;
            const float fw = ok ? f4.w : 0.f;
            const float2 m0 = *(const float2*)(mb + (size_t)k * HO * WO);       // row 2h
            const float2 m1 = *(const float2*)(mb + (size_t)k * HO * WO + WO);  // row 2h+1
            acc[0][0].x += fx * m0.x;  acc[0][0].y += fx * m0.y;
            acc[0][1].x += fx * m1.x;  acc[0][1].y += fx * m1.y;
            acc[1][0].x += fy * m0.x;  acc[1][0].y += fy * m0.y;
            acc[1][1].x += fy * m1.x;  acc[1][1].y += fy * m1.y;
            acc[2][0].x += fz * m0.x;  acc[2][0].y += fz * m0.y;
            acc[2][1].x += fz * m1.x;  acc[2][1].y += fz * m1.y;
            acc[3][0].x += fw * m0.x;  acc[3][0].y += fw * m0.y;
            acc[3][1].x += fw * m1.x;  acc[3][1].y += fw * m1.y;
        }
    }

    // ---- store: 4 ch x 2 rows, float2 (both q), coalesced ----
    float* ob = out + ((size_t)n * CIN + c0 + g * GC) * HO * WO
                    + (size_t)(2 * h) * WO + 2 * lane;
    #pragma unroll
    for (int ci = 0; ci < GC; ++ci) {
        *(float2*)(ob + (size_t)ci * HO * WO)      = acc[ci][0];
        *(float2*)(ob + (size_t)ci * HO * WO + WO) = acc[ci][1];
    }
}

extern "C" void kernel_launch(void* const* d_in, const int* in_sizes, int n_in,
                              void* d_out, int out_size, void* d_ws, size_t ws_size,
                              hipStream_t stream) {
    const float* feat  = (const float*)d_in[0];
    const float* masks = (const float*)d_in[1];
    float* out = (float*)d_out;

    dim3 grid(HH, CIN / CH_PER_BLOCK, 8);   // (h-swizzled, c-group, n) = (64, 8, 8)
    dim3 block(256);
    carafe_fwd<<<grid, block, 0, stream>>>(feat, masks, out);
}